// Round 1
// baseline (427.857 us; speedup 1.0000x reference)
//
#include <hip/hip_runtime.h>
#include <cstdint>
#include <cstddef>

#define GK0 0.7978845608028654f
#define GC1 0.044715f

typedef __attribute__((ext_vector_type(8))) short short8;
typedef __attribute__((ext_vector_type(4))) float floatx4;

__device__ __forceinline__ unsigned short f2bf(float f) {
  union { float f; unsigned int u; } v; v.f = f;
  unsigned int r = v.u + 0x7fffu + ((v.u >> 16) & 1u);   // RNE
  return (unsigned short)(r >> 16);
}

// async 16B global->LDS (LDS dest = wave-uniform base + lane*16; global src per-lane)
__device__ __forceinline__ void gl_lds16(const unsigned short* g, unsigned short* l) {
  __builtin_amdgcn_global_load_lds(
      (const __attribute__((address_space(1))) unsigned int*)g,
      (__attribute__((address_space(3))) unsigned int*)l, 16, 0, 0);
}

// ---- weights: [co][ci][3][3] f32 -> wt[khw][co][ci] bf16; also zero out ----
__global__ void k_wt(const float* __restrict__ w, unsigned short* __restrict__ wt,
                     float* __restrict__ out) {
  if (blockIdx.x == 0) {
    for (int i = threadIdx.x; i < 32 * 128; i += 256) out[i] = 0.0f;
  }
  int t = blockIdx.x * 256 + threadIdx.x;
  if (t >= 128 * 64 * 9) return;
  int co = t / 576; int r = t - co * 576; int ci = r / 9; int khw = r - ci * 9;
  wt[(khw * 128 + co) * 64 + ci] = f2bf(w[t]);
}

// ---- phase 1: NCHW fp32 -> NHWC bf16  xb[b][h][w][ci] ----
// grid (128 h, 32 b), block 256: one h-row per block (4x block parallelism vs the
// old 4-row serial loop, 1 barrier/row instead of 2). LDS tile XOR-swizzled by
// (ci>>3): the read stride is 8 rows * 528 B == 0 mod 128 B, so the +4-float pad
// alone left an 8-way b32 read conflict; the swizzle spreads the 8 oct-lanes
// across 8 distinct 16B slots (write side stays conflict-free: w4 spans all slots).
__global__ __launch_bounds__(256) void k_xt(const float* __restrict__ x,
                                            unsigned short* __restrict__ xb) {
  __shared__ float tile[64 * 132];
  const int tid = threadIdx.x, lane = tid & 63, wv = tid >> 6;
  const int b = blockIdx.y, h = blockIdx.x;
  const int w4 = lane & 31, cih = lane >> 5;

#pragma unroll
  for (int j = 0; j < 8; j++) {                        // load 64ci x 128w fp32
    const int ci = wv * 16 + 2 * j + cih;
    float4 f = *(const float4*)(x + ((size_t)(b * 64 + ci) * 128 + h) * 128 + 4 * w4);
    *(float4*)((char*)tile + ci * 528 + ((16 * w4) ^ (((ci >> 3) & 7) << 4))) = f;
  }
  __syncthreads();
  unsigned short* orow = xb + ((size_t)b * 128 + h) * 8192;
  const int oct = tid & 7, wlo = tid >> 3;             // wlo in 0..31 across block
#pragma unroll
  for (int it = 0; it < 4; it++) {
    const int w = wlo + 32 * it;
    short8 v;
#pragma unroll
    for (int j = 0; j < 8; j++) {
      const float f =
          *(const float*)((const char*)tile + (8 * oct + j) * 528 + ((4 * w) ^ (oct << 4)));
      v[j] = (short)f2bf(f);
    }
    *(short8*)(orow + w * 64 + oct * 8) = v;           // 16B/lane, contiguous
  }
}

// ---- phase 2: implicit-GEMM conv + fused bias/GELU/pool, kh-merged ----
// grid (2 w-halves, 63 h-pairs, 32 b), block 256 (4 waves).
// Tile M=128co x N=128pos (2 h-rows x 64 w). K-loop = 3 kh steps (kw taps merged:
// one staged 66-pos row segment serves all 3 kw shifts). Per step: 96 MFMA/wave
// between barriers (was 32), B double-buffered in LDS w/ XOR-swizzle (pre-swizzled
// global source since global_load_lds writes linearly), A (weights, 144 KB total,
// L1/L2-resident) loaded straight into VGPRs -- no A staging, no A barrier.
__global__ __launch_bounds__(256, 2) void k_conv(
    const unsigned short* __restrict__ xb, const unsigned short* __restrict__ wt,
    const float* __restrict__ bias, float* __restrict__ out) {
  __shared__ __align__(16) unsigned short Bs[2][9216];  // [buf][rh(2)][pos(72)][ci(64)]
  const int tid = threadIdx.x, lane = tid & 63, wv = tid >> 6;
  const int w0 = blockIdx.x * 64, h0 = blockIdx.y * 2, b = blockIdx.z;
  const int wm = wv & 1, wn = wv >> 1;                  // co-half, h-row
  const int m = lane & 15, q = lane >> 4;
  // staging source pre-swizzle: lane l writes LDS bytes [base+16l); row-within-8 is
  // l>>3, so source 16B slot = (l&7) ^ (l>>3)  (involution; read side XORs the same)
  const int swz = ((lane >> 3) << 6) + (((lane & 7) ^ (lane >> 3)) << 3);

  floatx4 acc[4][4];
#pragma unroll
  for (int i = 0; i < 4; i++)
#pragma unroll
    for (int j = 0; j < 4; j++) acc[i][j] = (floatx4){0.f, 0.f, 0.f, 0.f};

  const unsigned short* xbb = xb + (size_t)b * 128 * 8192;

  // stage rows (h0+kh+rh), positions w0..w0+71 (only 0..65 consumed; tail is
  // alignment padding -- overreads stay inside xb + its 4 KB slack)
  auto stage = [&](unsigned short* bs, int row0) {
    for (int c = wv; c < 18; c += 4) {                  // 18 x 1KB chunks
      const int rh = (c >= 9) ? 1 : 0;
      const int j = c - 9 * rh;
      gl_lds16(xbb + ((size_t)((row0 + rh) * 128 + w0) << 6) + j * 512 + swz,
               bs + rh * 4608 + j * 512);
    }
  };

  stage(Bs[0], h0);
  __syncthreads();

#pragma unroll
  for (int kh = 0; kh < 3; kh++) {
    if (kh < 2) stage(Bs[(kh + 1) & 1], h0 + kh + 1);   // prefetch next kh (T3 2-phase)
    const unsigned short* bsr = Bs[kh & 1] + wn * 4608;
#pragma unroll
    for (int kw = 0; kw < 3; kw++) {
      const int khw = kh * 3 + kw;
      const int xr = ((m + kw) & 7) << 3;               // pos&7 == (m+kw)&7 (nt*16%8==0)
#pragma unroll
      for (int half = 0; half < 2; half++) {
        const int colb = half * 32 + q * 8;
        short8 a[4], bf[4];
#pragma unroll
        for (int mt = 0; mt < 4; mt++)                  // A: global->reg, 16B contiguous
          a[mt] = *(const short8*)(wt + khw * 8192 + (wm * 64 + mt * 16 + m) * 64 + colb);
#pragma unroll
        for (int nt = 0; nt < 4; nt++)                  // B: swizzled ds_read_b128
          bf[nt] = *(const short8*)(bsr + (nt * 16 + m + kw) * 64 + (colb ^ xr));
#pragma unroll
        for (int mt = 0; mt < 4; mt++)
#pragma unroll
          for (int nt = 0; nt < 4; nt++)
            acc[mt][nt] =
                __builtin_amdgcn_mfma_f32_16x16x32_bf16(a[mt], bf[nt], acc[mt][nt], 0, 0, 0);
      }
    }
    __syncthreads();                                    // drains stage vmcnt; buffer swap
  }

  // epilogue: bias + fast tanh-GELU (y*sigmoid(2u)) + masked pool
  // D layout: col n = wn*64 + nt*16 + (lane&15) -> w' = nt*16+m; row co = q*4+r
  const float inv_area = 1.0f / (126.0f * 126.0f);
  float* orow = out + b * 128;
#pragma unroll
  for (int mt = 0; mt < 4; mt++)
#pragma unroll
    for (int r2 = 0; r2 < 4; r2++) {
      const int co = wm * 64 + mt * 16 + q * 4 + r2;
      const float bv = bias[co];
      float s = 0.f;
#pragma unroll
      for (int nt = 0; nt < 4; nt++) {
        float y = acc[mt][nt][r2] + bv;
        float u = GK0 * (y + GC1 * y * y * y);
        float e = __expf(-2.0f * u);
        float g = y * __builtin_amdgcn_rcpf(1.0f + e);  // == 0.5y(1+tanh u)
        if (w0 + nt * 16 + m < 126) s += g;             // mask padded w' = 126,127
      }
#pragma unroll
      for (int d = 1; d < 16; d <<= 1) s += __shfl_xor(s, d, 64);
      if (m == 0) atomicAdd(&orow[co], s * inv_area);
    }
}

extern "C" void kernel_launch(void* const* d_in, const int* in_sizes, int n_in,
                              void* d_out, int out_size, void* d_ws, size_t ws_size,
                              hipStream_t stream) {
  const float* x    = (const float*)d_in[0];
  const float* w    = (const float*)d_in[1];
  const float* bias = (const float*)d_in[2];
  float* out = (float*)d_out;

  const size_t xb_elems = (size_t)32 * 128 * 8192;      // 64 MiB bf16 NHWC
  unsigned short* xbuf = (unsigned short*)d_ws;
  unsigned short* wbuf = xbuf + xb_elems + 2048;        // 4 KB slack (B halo overreads)
  if (ws_size < xb_elems * 2 + 4096 + (size_t)9 * 128 * 64 * 2) return;

  k_wt<<<288, 256, 0, stream>>>(w, wbuf, out);
  k_xt<<<dim3(128, 32), 256, 0, stream>>>(x, xbuf);
  k_conv<<<dim3(2, 63, 32), 256, 0, stream>>>(xbuf, wbuf, bias, out);
}